// Round 3
// baseline (406.137 us; speedup 1.0000x reference)
//
#include <hip/hip_runtime.h>

#define B_N 4096
#define T_N 64
#define K_N 512
#define D_N 64
#define KC 64              // codes per LDS chunk
#define NCHUNK (K_N / KC)  // 8

// ws layout:
//   [0, 131072)        : c2[t*K+k]  (32768 floats)
//   [131072, 262144)   : used[t*K+k] (32768 uints)
//   [262144, 262152)   : loss_sum (double)   (zeroed together with used via memset)

// |c|^2 per code: pre-rounded squares, sequential ascending-d adds (matches jnp).
__global__ __launch_bounds__(256) void c2_kernel(const float* __restrict__ cb,
                                                 float* __restrict__ c2) {
    int i = blockIdx.x * 256 + threadIdx.x;   // < 32768
    const float4* c = reinterpret_cast<const float4*>(cb + (size_t)i * D_N);
    float s = 0.0f;
#pragma unroll
    for (int j = 0; j < 16; ++j) {
        float4 v = c[j];
        s = __fadd_rn(s, __fmul_rn(v.x, v.x));
        s = __fadd_rn(s, __fmul_rn(v.y, v.y));
        s = __fadd_rn(s, __fmul_rn(v.z, v.z));
        s = __fadd_rn(s, __fmul_rn(v.w, v.w));
    }
    c2[i] = s;
}

// chain helper: 4 sequential FMAs of one float4 into acc (ascending d order)
#define FMA4(acc, zq, c4)                          \
    acc = __builtin_fmaf((zq).x, (c4).x, acc);     \
    acc = __builtin_fmaf((zq).y, (c4).y, acc);     \
    acc = __builtin_fmaf((zq).z, (c4).z, acc);     \
    acc = __builtin_fmaf((zq).w, (c4).w, acc);

__global__ __launch_bounds__(256, 2) void vq_main(const float* __restrict__ z_e,
                                                  const float* __restrict__ cb,
                                                  const float* __restrict__ c2,
                                                  float* __restrict__ zq_out,
                                                  float* __restrict__ tok_out,
                                                  unsigned* __restrict__ used,
                                                  double* __restrict__ loss_sum) {
    const int t   = blockIdx.y;
    const int tid = threadIdx.x;
    const int b0  = blockIdx.x * 512 + 2 * tid;
    const int b1  = b0 + 1;

    __shared__ __align__(16) float cbuf[2][KC * D_N];  // 2 x 16 KB
    __shared__ __align__(16) float c2buf[2][KC];

    // z rows -> registers as float4 (16 each)
    float4 z0[16], z1[16];
    const float4* zr0 = reinterpret_cast<const float4*>(z_e + ((size_t)b0 * T_N + t) * D_N);
    const float4* zr1 = reinterpret_cast<const float4*>(z_e + ((size_t)b1 * T_N + t) * D_N);
#pragma unroll
    for (int j = 0; j < 16; ++j) { z0[j] = zr0[j]; z1[j] = zr1[j]; }

    // A = sum(z*z): pre-rounded products, sequential ascending-d adds.
    float A0 = 0.0f, A1 = 0.0f;
#pragma unroll
    for (int j = 0; j < 16; ++j) {
        A0 = __fadd_rn(A0, __fmul_rn(z0[j].x, z0[j].x));
        A0 = __fadd_rn(A0, __fmul_rn(z0[j].y, z0[j].y));
        A0 = __fadd_rn(A0, __fmul_rn(z0[j].z, z0[j].z));
        A0 = __fadd_rn(A0, __fmul_rn(z0[j].w, z0[j].w));
    }
#pragma unroll
    for (int j = 0; j < 16; ++j) {
        A1 = __fadd_rn(A1, __fmul_rn(z1[j].x, z1[j].x));
        A1 = __fadd_rn(A1, __fmul_rn(z1[j].y, z1[j].y));
        A1 = __fadd_rn(A1, __fmul_rn(z1[j].z, z1[j].z));
        A1 = __fadd_rn(A1, __fmul_rn(z1[j].w, z1[j].w));
    }

    const float* cbt = cb + (size_t)t * K_N * D_N;
    const float* c2t = c2 + t * K_N;

    float4 pf[4];
    float4 c2pf;
    auto issue = [&](int c) {
        const float4* src = reinterpret_cast<const float4*>(cbt + (size_t)c * KC * D_N);
#pragma unroll
        for (int j = 0; j < 4; ++j) pf[j] = src[j * 256 + tid];
        if (tid < 16) c2pf = reinterpret_cast<const float4*>(c2t + c * KC)[tid];
    };
    auto writebuf = [&](int buf) {
#pragma unroll
        for (int j = 0; j < 4; ++j) reinterpret_cast<float4*>(cbuf[buf])[j * 256 + tid] = pf[j];
        if (tid < 16) reinterpret_cast<float4*>(c2buf[buf])[tid] = c2pf;
    };

    issue(0);
    writebuf(0);
    __syncthreads();

    float best0 = __builtin_inff(), best1 = __builtin_inff();
    int tok0 = 0, tok1 = 0;

    for (int c = 0; c < NCHUNK; ++c) {
        if (c < NCHUNK - 1) issue(c + 1);   // global loads in flight over compute
        const float4* cc4 = reinterpret_cast<const float4*>(cbuf[c & 1]);
        const float* c2c  = c2buf[c & 1];

        // software pipeline: lo half in LO regs, hi half in HI regs
        float4 LO[8], HI[8];
#pragma unroll
        for (int j = 0; j < 8; ++j) LO[j] = cc4[j];           // code 0 lo half

#pragma unroll 2
        for (int kk = 0; kk < KC; ++kk) {
            const float4* row  = cc4 + kk * 16;
            const float4* nrow = cc4 + ((kk + 1) & (KC - 1)) * 16;
            // issue hi-half loads (ds_read_b128 x8)
#pragma unroll
            for (int j = 0; j < 8; ++j) HI[j] = row[8 + j];
            // FMA lo half (d = 0..31), both chains, while HI loads in flight
            float a0 = 0.0f, a1 = 0.0f;
#pragma unroll
            for (int j = 0; j < 8; ++j) { FMA4(a0, z0[j], LO[j]); FMA4(a1, z1[j], LO[j]); }
            // issue next code's lo-half loads
#pragma unroll
            for (int j = 0; j < 8; ++j) LO[j] = nrow[j];
            // FMA hi half (d = 32..63)
#pragma unroll
            for (int j = 0; j < 8; ++j) { FMA4(a0, z0[8 + j], HI[j]); FMA4(a1, z1[8 + j], HI[j]); }

            float c2k = c2c[kk];
            float dist0 = __fadd_rn(__fsub_rn(A0, __fmul_rn(2.0f, a0)), c2k);
            float dist1 = __fadd_rn(__fsub_rn(A1, __fmul_rn(2.0f, a1)), c2k);
            int k = c * KC + kk;
            if (dist0 < best0) { best0 = dist0; tok0 = k; }   // strict <: first-occurrence
            if (dist1 < best1) { best1 = dist1; tok1 = k; }
        }
        if (c < NCHUNK - 1) {
            __syncthreads();
            writebuf((c + 1) & 1);
            __syncthreads();
        }
    }

    // Epilogue: z_q_st = winning codebook row; loss in double.
    const float4* q0 = reinterpret_cast<const float4*>(cbt + (size_t)tok0 * D_N);
    const float4* q1 = reinterpret_cast<const float4*>(cbt + (size_t)tok1 * D_N);
    float4* zq0 = reinterpret_cast<float4*>(zq_out + ((size_t)b0 * T_N + t) * D_N);
    float4* zq1 = reinterpret_cast<float4*>(zq_out + ((size_t)b1 * T_N + t) * D_N);
    double ld = 0.0;
#pragma unroll
    for (int j = 0; j < 16; ++j) {
        float4 qv = q0[j];
        zq0[j] = qv;
        float d0 = z0[j].x - qv.x, d1 = z0[j].y - qv.y;
        float d2 = z0[j].z - qv.z, d3 = z0[j].w - qv.w;
        ld += (double)d0*d0 + (double)d1*d1 + (double)d2*d2 + (double)d3*d3;
    }
#pragma unroll
    for (int j = 0; j < 16; ++j) {
        float4 qv = q1[j];
        zq1[j] = qv;
        float d0 = z1[j].x - qv.x, d1 = z1[j].y - qv.y;
        float d2 = z1[j].z - qv.z, d3 = z1[j].w - qv.w;
        ld += (double)d0*d0 + (double)d1*d1 + (double)d2*d2 + (double)d3*d3;
    }
    tok_out[(size_t)b0 * T_N + t] = (float)tok0;
    tok_out[(size_t)b1 * T_N + t] = (float)tok1;
    used[t * K_N + tok0] = 1u;
    used[t * K_N + tok1] = 1u;

    __syncthreads();
    double* red = reinterpret_cast<double*>(cbuf[0]);
    red[tid] = ld;
    __syncthreads();
    for (int s = 128; s > 0; s >>= 1) {
        if (tid < s) red[tid] += red[tid + s];
        __syncthreads();
    }
    if (tid == 0) atomicAdd(loss_sum, red[0]);
}

__global__ __launch_bounds__(1024) void finalize_kernel(const unsigned* __restrict__ used,
                                                        const double* __restrict__ loss_sum,
                                                        float* __restrict__ out) {
    __shared__ unsigned s[1024];
    const uint4* u4 = reinterpret_cast<const uint4*>(used);
    unsigned c = 0;
#pragma unroll
    for (int i = 0; i < 8; ++i) {
        uint4 v = u4[threadIdx.x + i * 1024];
        c += v.x + v.y + v.z + v.w;
    }
    s[threadIdx.x] = c;
    __syncthreads();
    for (int st = 512; st > 0; st >>= 1) {
        if (threadIdx.x < st) s[threadIdx.x] += s[threadIdx.x + st];
        __syncthreads();
    }
    if (threadIdx.x == 0) {
        const size_t base = (size_t)B_N * T_N * D_N + (size_t)B_N * T_N;
        out[base]     = (float)(0.25 * (*loss_sum) / (double)((size_t)B_N * T_N * D_N));
        out[base + 1] = (float)s[0] / (float)(T_N * K_N);
    }
}

extern "C" void kernel_launch(void* const* d_in, const int* in_sizes, int n_in,
                              void* d_out, int out_size, void* d_ws, size_t ws_size,
                              hipStream_t stream) {
    const float* z_e = (const float*)d_in[0];
    const float* cb  = (const float*)d_in[1];
    float* out = (float*)d_out;

    float*    c2   = (float*)d_ws;
    unsigned* used = (unsigned*)((char*)d_ws + 131072);
    double*   loss = (double*)((char*)d_ws + 262144);

    // zero used[] and loss_sum in one async memset (contiguous, all-zero bytes)
    hipMemsetAsync(used, 0, 131072 + 8, stream);
    c2_kernel<<<128, 256, 0, stream>>>(cb, c2);

    float* tok_out = out + (size_t)B_N * T_N * D_N;
    vq_main<<<dim3(B_N / 512, T_N), 256, 0, stream>>>(z_e, cb, c2, out, tok_out, used, loss);

    finalize_kernel<<<1, 1024, 0, stream>>>(used, loss, out);
}